// Round 8
// baseline (505.626 us; speedup 1.0000x reference)
//
#include <hip/hip_runtime.h>

#define D1 8
#define D2 16
#define HH 64
#define WW 64
#define SPATIAL (D1*D2*HH*WW)   // 524288
#define EPS 1e-5f
#define NEG 0.2f

typedef unsigned short u16;
typedef __attribute__((ext_vector_type(8))) short s16x8;
typedef __attribute__((ext_vector_type(8))) unsigned short u16x8;
typedef __attribute__((ext_vector_type(4))) unsigned short u16x4;
typedef __attribute__((ext_vector_type(4))) float f32x4;

__device__ __forceinline__ u16 f2bf(float f) {
    unsigned int u = __builtin_bit_cast(unsigned int, f);
    return (u16)((u + 0x7FFFu + ((u >> 16) & 1u)) >> 16);   // RNE
}
__device__ __forceinline__ float bf2f(u16 u) {
    unsigned int v = ((unsigned int)u) << 16;
    return __builtin_bit_cast(float, v);
}
__device__ __forceinline__ float leaky(float x) {
    return x >= 0.f ? x : NEG * x;
}

// XCD swizzle: b-PAIR per XCD; ht/wt/a consecutive on one XCD. Grid 2048.
__device__ __forceinline__ void decode_block(int flat, int& a, int& b,
                                             int& h0, int& w0) {
    int xcd  = flat & 7;
    int slot = flat >> 3;
    int ht   = slot & 7;
    int wt   = (slot >> 3) & 1;
    int b0   = (slot >> 4) & 1;
    a        = (slot >> 5) & 7;
    b        = xcd * 2 + b0;
    h0       = ht * 8;
    w0       = wt * 32;
}

// ---------------------------------------------------------------------------
// prep: fused imgtrans (blocks 0..2047) + wtrans1 (2048..2263) +
//       wtrans2 (2264..2587) + stats-zero (2588).
// w1t: [p(9)][dh(3)][grp(2)][co(32)][k(32)]
// w2t: [p(9)][tap(9)][co(32)][ci(32)]
// imgT: [spatial][ci16] channel-last bf16
// ---------------------------------------------------------------------------
__global__ __launch_bounds__(256)
void prep(const float* __restrict__ img, const float* __restrict__ w1,
          const float* __restrict__ w2, u16* __restrict__ imgT,
          u16* __restrict__ w1t, u16* __restrict__ w2t, float* __restrict__ st)
{
    const int bid = blockIdx.x;
    const int tid = threadIdx.x;
    if (bid < 2048) {                          // image transpose
        int p = bid * 256 + tid;
        u16 r[16];
        #pragma unroll
        for (int c = 0; c < 16; ++c)
            r[c] = f2bf(img[(size_t)c * SPATIAL + p]);
        u16x8 lo, hi;
        #pragma unroll
        for (int j = 0; j < 8; ++j) { lo[j] = r[j]; hi[j] = r[8 + j]; }
        u16x8* dst = (u16x8*)(imgT + (size_t)p * 16);
        dst[0] = lo;
        dst[1] = hi;
    } else if (bid < 2264) {                   // w1 transform
        int i = (bid - 2048) * 256 + tid;
        if (i >= 55296) return;
        int k    = i & 31;
        int co   = (i >> 5) & 31;
        int grp  = (i >> 10) & 1;
        int rest = i >> 11;           // p*3+dh
        int dh   = rest % 3;
        int p    = rest / 3;
        int da = p / 3, db = p % 3;
        float v = 0.f;
        if (grp == 0) {
            int dw = k >> 4, ci = k & 15;
            v = w1[((((co * 16 + ci) * 3 + da) * 3 + db) * 3 + dh) * 3 + dw];
        } else if (k < 16) {
            v = w1[((((co * 16 + k) * 3 + da) * 3 + db) * 3 + dh) * 3 + 2];
        }
        w1t[i] = f2bf(v);
    } else if (bid < 2588) {                   // w2 transform
        int i = (bid - 2264) * 256 + tid;
        if (i >= 82944) return;
        int ci = i & 31;
        int co = (i >> 5) & 31;
        int t  = (i >> 10) % 9;
        int p  = (i >> 10) / 9;
        int da = p / 3, db = p % 3, dh = t / 3, dw = t % 3;
        w2t[i] = f2bf(w2[((((co * 32 + ci) * 3 + da) * 3 + db) * 3 + dh) * 3 + dw]);
    } else {                                   // stats zero
        if (tid < 128) st[tid] = 0.f;
    }
}

// ---------------------------------------------------------------------------
// Conv1: Cin=16, K = dw(2)x ci(16) packing + dw2 group. 8h x 32w tile.
// LDS: 340 pos (10 rows x 34 cols) x 24 u16 = 16,320 B -> high occupancy.
// Wave: wseg=(wv&1)*16, rows (wv>>1)*4..+3; acc[4][2]. dh-shared A-frags.
// ---------------------------------------------------------------------------
__global__ __launch_bounds__(256, 5)
void conv1_mfma(const u16* __restrict__ xT, const u16* __restrict__ w1t,
                u16* __restrict__ y1, float* __restrict__ st1)
{
    __shared__ __align__(16) u16 lds[340 * 24];   // 16320 B
    __shared__ float sred[64];

    const int tid = threadIdx.x;
    int a, b, h0, w0;
    decode_block(blockIdx.x, a, b, h0, w0);
    const int lane = tid & 63;
    const int wv   = tid >> 6;
    const int kq   = lane >> 4;
    const int m    = lane & 15;
    const int wsl  = (wv & 1) << 4;     // wave w-subsegment (local)
    const int r0   = (wv >> 1) << 2;    // wave row base (local)

    unsigned pm = 0;
    #pragma unroll
    for (int p = 0; p < 9; ++p) {
        int ap = a + p / 3 - 1, bp = b + p % 3 - 1;
        if (ap >= 0 && ap < D1 && bp >= 0 && bp < D2) pm |= 1u << p;
    }

    // staging offsets: 680 granules (340 pos x 2), 3 chunks/thread
    const int p0 = tid >> 1, g = tid & 1;
    unsigned vmask = 0;
    int goff[3];
    #pragma unroll
    for (int k = 0; k < 3; ++k) {
        int pos = p0 + 128 * k;
        int row = pos / 34, col = pos - row * 34;
        int h = h0 - 1 + row, w = w0 + col - 1;
        bool v = (pos < 340) && w >= 0 && w < WW && h >= 0 && h < HH;
        goff[k] = v ? (h * WW + w) * 16 + g * 8 : 0;
        vmask |= (unsigned)v << k;
    }
    const int lbase = p0 * 24 + g * 8;

    // zero pad/OOB cells once
    for (int e = tid; e < 340; e += 256) {
        int row = e / 34, col = e - row * 34;
        int h = h0 - 1 + row, w = w0 + col - 1;
        if (w < 0 || w >= WW || h < 0 || h >= HH) {
            u16x8 z = (u16x8)0;
            *(u16x8*)&lds[e * 24]     = z;
            *(u16x8*)&lds[e * 24 + 8] = z;
        }
    }

    f32x4 acc[4][2];
    #pragma unroll
    for (int i = 0; i < 4; ++i)
        #pragma unroll
        for (int nt = 0; nt < 2; ++nt)
            acc[i][nt] = (f32x4)0.f;

    int p = 0;
    while (!((pm >> p) & 1)) ++p;

    u16x8 pf[3];
    {
        int ap = a + p / 3 - 1, bp = b + p % 3 - 1;
        const u16* src = xT + (size_t)(ap * D2 + bp) * (HH * WW * 16);
        #pragma unroll
        for (int k = 0; k < 3; ++k)
            if ((vmask >> k) & 1) pf[k] = *(const u16x8*)(src + goff[k]);
    }

    while (p < 9) {
        int pn = p + 1;
        while (pn < 9 && !((pm >> pn) & 1)) ++pn;

        #pragma unroll
        for (int k = 0; k < 3; ++k)
            if ((vmask >> k) & 1) *(u16x8*)&lds[lbase + k * 3072] = pf[k];
        __syncthreads();

        const u16* srcn = nullptr;
        if (pn < 9)
            srcn = xT + (size_t)((a + pn / 3 - 1) * D2 + (b + pn % 3 - 1))
                      * (HH * WW * 16);

        const u16* wbase = w1t + p * 6144;
        #pragma unroll
        for (int grp = 0; grp < 2; ++grp) {
            // B-frags first: first vmem after barrier
            s16x8 bf[3][2];
            #pragma unroll
            for (int dh = 0; dh < 3; ++dh) {
                const u16* wb = wbase + (dh * 2 + grp) * 1024;
                bf[dh][0] = *(const s16x8*)(wb + m * 32 + kq * 8);
                bf[dh][1] = *(const s16x8*)(wb + (m + 16) * 32 + kq * 8);
            }
            const int cshift = (grp == 0) ? (kq >> 1) : 2;
            const int ebase  = (kq & 1) * 8;
            #pragma unroll
            for (int xi = 0; xi < 6; ++xi) {
                int pos = (r0 + xi) * 34 + wsl + m + cshift;
                s16x8 af = *(const s16x8*)&lds[pos * 24 + ebase];
                #pragma unroll
                for (int dh = 0; dh < 3; ++dh) {
                    int i = xi - dh;
                    if (i >= 0 && i < 4) {
                        acc[i][0] = __builtin_amdgcn_mfma_f32_16x16x32_bf16(af, bf[dh][0], acc[i][0], 0, 0, 0);
                        acc[i][1] = __builtin_amdgcn_mfma_f32_16x16x32_bf16(af, bf[dh][1], acc[i][1], 0, 0, 0);
                    }
                }
            }
            // progressive prefetch of next plane
            if (pn < 9) {
                const int k0 = grp * 1, k1 = grp ? 3 : 1;
                #pragma unroll
                for (int k = k0; k < k1; ++k)
                    if ((vmask >> k) & 1) pf[k] = *(const u16x8*)(srcn + goff[k]);
            }
        }
        __syncthreads();
        p = pn;
    }

    // epilogue: channel-last bf16 store + fused per-channel stats
    if (tid < 64) sred[tid] = 0.f;
    __syncthreads();

    float s[2] = {0.f, 0.f}, s2[2] = {0.f, 0.f};
    const size_t plane_out = (size_t)(a * D2 + b) * (HH * WW);
    #pragma unroll
    for (int i = 0; i < 4; ++i) {
        int h  = h0 + r0 + i;
        int w  = w0 + wsl + kq * 4;
        #pragma unroll
        for (int nt = 0; nt < 2; ++nt) {
            int co = m + nt * 16;
            #pragma unroll
            for (int reg = 0; reg < 4; ++reg) {
                float v = acc[i][nt][reg];
                s[nt]  += v;
                s2[nt] += v * v;
                y1[(plane_out + h * WW + (w + reg)) * 32 + co] = f2bf(v);
            }
        }
    }
    #pragma unroll
    for (int nt = 0; nt < 2; ++nt) {
        s[nt]  += __shfl_xor(s[nt], 16);  s[nt]  += __shfl_xor(s[nt], 32);
        s2[nt] += __shfl_xor(s2[nt], 16); s2[nt] += __shfl_xor(s2[nt], 32);
    }
    if (kq == 0) {
        atomicAdd(&sred[m * 2],            s[0]);
        atomicAdd(&sred[m * 2 + 1],        s2[0]);
        atomicAdd(&sred[(m + 16) * 2],     s[1]);
        atomicAdd(&sred[(m + 16) * 2 + 1], s2[1]);
    }
    __syncthreads();
    if (tid < 64) atomicAdd(&st1[tid], sred[tid]);
}

// ---------------------------------------------------------------------------
// norm1: in-place instance-norm + leaky on y1 (channel-last bf16).
// ---------------------------------------------------------------------------
__global__ __launch_bounds__(256)
void norm1_kernel(u16* __restrict__ y1, const float* __restrict__ st1)
{
    const int tid = threadIdx.x;
    const int q   = tid & 3;
    const float invN = 1.f / (float)SPATIAL;
    float mean[8], scl[8];
    #pragma unroll
    for (int j = 0; j < 8; ++j) {
        int ci  = q * 8 + j;
        float mu = st1[ci * 2] * invN;
        float va = st1[ci * 2 + 1] * invN - mu * mu;
        mean[j] = mu;
        scl[j]  = rsqrtf(va + EPS);
    }
    #pragma unroll
    for (int j4 = 0; j4 < 4; ++j4) {
        size_t gidx = (size_t)blockIdx.x * 1024 + j4 * 256 + tid;
        u16x8* ptr = (u16x8*)(y1 + gidx * 8);
        u16x8 v = *ptr;
        u16x8 o;
        #pragma unroll
        for (int j = 0; j < 8; ++j)
            o[j] = f2bf(leaky((bf2f(v[j]) - mean[j]) * scl[j]));
        *ptr = o;
    }
}

// ---------------------------------------------------------------------------
// Conv2: Cin=32, 8h x 32w tile. LDS: 340 pos x 40 u16 = 27,200 B.
// Wave: wseg=(wv&1)*16, rows (wv>>1)*4..+3; acc[4][2]. dh-shared A-frags.
// ---------------------------------------------------------------------------
__global__ __launch_bounds__(256, 5)
void conv2_mfma(const u16* __restrict__ y1, const u16* __restrict__ w2t,
                u16* __restrict__ y2, float* __restrict__ st2)
{
    __shared__ __align__(16) u16 lds[340 * 40];   // 27200 B
    __shared__ float sred[64];

    const int tid = threadIdx.x;
    int a, b, h0, w0;
    decode_block(blockIdx.x, a, b, h0, w0);
    const int lane = tid & 63;
    const int wv   = tid >> 6;
    const int kq   = lane >> 4;
    const int m    = lane & 15;
    const int wsl  = (wv & 1) << 4;
    const int r0   = (wv >> 1) << 2;

    unsigned pm = 0;
    #pragma unroll
    for (int p = 0; p < 9; ++p) {
        int ap = a + p / 3 - 1, bp = b + p % 3 - 1;
        if (ap >= 0 && ap < D1 && bp >= 0 && bp < D2) pm |= 1u << p;
    }

    // staging offsets: 1360 granules (340 pos x 4), 6 chunks/thread
    const int p0 = tid >> 2, q = tid & 3;
    unsigned vmask = 0;
    int goff[6];
    #pragma unroll
    for (int k = 0; k < 6; ++k) {
        int pos = p0 + 64 * k;
        int row = pos / 34, col = pos - row * 34;
        int h = h0 - 1 + row, w = w0 + col - 1;
        bool v = (pos < 340) && w >= 0 && w < WW && h >= 0 && h < HH;
        goff[k] = v ? (h * WW + w) * 32 + q * 8 : 0;
        vmask |= (unsigned)v << k;
    }
    const int lbase = p0 * 40 + q * 8;

    for (int e = tid; e < 340; e += 256) {
        int row = e / 34, col = e - row * 34;
        int h = h0 - 1 + row, w = w0 + col - 1;
        if (w < 0 || w >= WW || h < 0 || h >= HH) {
            u16x8 z = (u16x8)0;
            #pragma unroll
            for (int gg = 0; gg < 4; ++gg)
                *(u16x8*)&lds[e * 40 + gg * 8] = z;
        }
    }

    f32x4 acc[4][2];
    #pragma unroll
    for (int i = 0; i < 4; ++i)
        #pragma unroll
        for (int nt = 0; nt < 2; ++nt)
            acc[i][nt] = (f32x4)0.f;

    int p = 0;
    while (!((pm >> p) & 1)) ++p;

    u16x8 pf[6];
    {
        int ap = a + p / 3 - 1, bp = b + p % 3 - 1;
        const u16* src = y1 + (size_t)(ap * D2 + bp) * (HH * WW * 32);
        #pragma unroll
        for (int k = 0; k < 6; ++k)
            if ((vmask >> k) & 1) pf[k] = *(const u16x8*)(src + goff[k]);
    }

    while (p < 9) {
        int pn = p + 1;
        while (pn < 9 && !((pm >> pn) & 1)) ++pn;

        #pragma unroll
        for (int k = 0; k < 6; ++k)
            if ((vmask >> k) & 1) *(u16x8*)&lds[lbase + k * 2560] = pf[k];
        __syncthreads();

        const u16* srcn = nullptr;
        if (pn < 9)
            srcn = y1 + (size_t)((a + pn / 3 - 1) * D2 + (b + pn % 3 - 1))
                      * (HH * WW * 32);

        const u16* wbase = w2t + p * 9216;
        #pragma unroll
        for (int dw = 0; dw < 3; ++dw) {
            // B-frags first: first vmem after barrier
            s16x8 bf[3][2];
            #pragma unroll
            for (int dh = 0; dh < 3; ++dh) {
                const u16* wb = wbase + (dh * 3 + dw) * 1024;
                bf[dh][0] = *(const s16x8*)(wb + m * 32 + kq * 8);
                bf[dh][1] = *(const s16x8*)(wb + (m + 16) * 32 + kq * 8);
            }
            #pragma unroll
            for (int xi = 0; xi < 6; ++xi) {
                int pos = (r0 + xi) * 34 + wsl + dw + m;
                s16x8 af = *(const s16x8*)&lds[pos * 40 + kq * 8];
                #pragma unroll
                for (int dh = 0; dh < 3; ++dh) {
                    int i = xi - dh;
                    if (i >= 0 && i < 4) {
                        acc[i][0] = __builtin_amdgcn_mfma_f32_16x16x32_bf16(af, bf[dh][0], acc[i][0], 0, 0, 0);
                        acc[i][1] = __builtin_amdgcn_mfma_f32_16x16x32_bf16(af, bf[dh][1], acc[i][1], 0, 0, 0);
                    }
                }
            }
            // progressive prefetch of next plane
            if (pn < 9) {
                #pragma unroll
                for (int k = dw * 2; k < dw * 2 + 2; ++k)
                    if ((vmask >> k) & 1) pf[k] = *(const u16x8*)(srcn + goff[k]);
            }
        }
        __syncthreads();
        p = pn;
    }

    // epilogue: channel-first bf16 + fused stats
    if (tid < 64) sred[tid] = 0.f;
    __syncthreads();

    float s[2] = {0.f, 0.f}, s2[2] = {0.f, 0.f};
    #pragma unroll
    for (int i = 0; i < 4; ++i) {
        int h = h0 + r0 + i;
        int w = w0 + wsl + kq * 4;
        #pragma unroll
        for (int nt = 0; nt < 2; ++nt) {
            int co = m + nt * 16;
            u16x4 pk;
            #pragma unroll
            for (int reg = 0; reg < 4; ++reg) {
                float v = acc[i][nt][reg];
                s[nt]  += v;
                s2[nt] += v * v;
                pk[reg] = f2bf(v);
            }
            size_t off = ((size_t)(co * D1 + a) * D2 + b) * (HH * WW) + h * WW + w;
            *(u16x4*)(y2 + off) = pk;
        }
    }
    #pragma unroll
    for (int nt = 0; nt < 2; ++nt) {
        s[nt]  += __shfl_xor(s[nt], 16);  s[nt]  += __shfl_xor(s[nt], 32);
        s2[nt] += __shfl_xor(s2[nt], 16); s2[nt] += __shfl_xor(s2[nt], 32);
    }
    if (kq == 0) {
        atomicAdd(&sred[m * 2],            s[0]);
        atomicAdd(&sred[m * 2 + 1],        s2[0]);
        atomicAdd(&sred[(m + 16) * 2],     s[1]);
        atomicAdd(&sred[(m + 16) * 2 + 1], s2[1]);
    }
    __syncthreads();
    if (tid < 64) atomicAdd(&st2[tid], sred[tid]);
}

// ---------------------------------------------------------------------------
// Final: norm + leaky, bf16 channel-first -> fp32 channel-first d_out
// ---------------------------------------------------------------------------
__global__ __launch_bounds__(256)
void norm2_kernel(const u16* __restrict__ y2, const float* __restrict__ st2,
                  float* __restrict__ out)
{
    size_t i4 = (size_t)blockIdx.x * 256 + threadIdx.x;
    int c = (int)(i4 >> 17);
    const float invN = 1.f / (float)SPATIAL;
    float mu = st2[c * 2] * invN;
    float va = st2[c * 2 + 1] * invN - mu * mu;
    float sc = rsqrtf(va + EPS);
    u16x4 v = *(const u16x4*)(y2 + i4 * 4);
    float4 o;
    o.x = leaky((bf2f(v[0]) - mu) * sc);
    o.y = leaky((bf2f(v[1]) - mu) * sc);
    o.z = leaky((bf2f(v[2]) - mu) * sc);
    o.w = leaky((bf2f(v[3]) - mu) * sc);
    *(float4*)(out + i4 * 4) = o;
}

// ---------------------------------------------------------------------------
extern "C" void kernel_launch(void* const* d_in, const int* in_sizes, int n_in,
                              void* d_out, int out_size, void* d_ws, size_t ws_size,
                              hipStream_t stream)
{
    const float* image = (const float*)d_in[0];
    const float* w1    = (const float*)d_in[1];
    const float* w2    = (const float*)d_in[2];
    float* out = (float*)d_out;

    // ws: [0,32MB) imgT (reused as y2) | [32MB,64MB) y1 | [64MB,+512B) stats
    u16*   imgT = (u16*)d_ws;
    u16*   y1   = (u16*)((char*)d_ws + 33554432);
    u16*   y2   = imgT;
    float* st   = (float*)((char*)d_ws + 67108864);
    float* st1  = st;
    float* st2  = st + 64;

    // weight tables live in d_out's tail; dead before norm2 overwrites d_out
    u16* w1t = (u16*)((char*)d_out + 66832384);   // 55296 bf16
    u16* w2t = (u16*)((char*)d_out + 66942976);   // 82944 bf16

    prep<<<2589, 256, 0, stream>>>(image, w1, w2, imgT, w1t, w2t, st);

    conv1_mfma<<<2048, 256, 0, stream>>>(imgT, w1t, y1, st1);
    norm1_kernel<<<2048, 256, 0, stream>>>(y1, st1);
    conv2_mfma<<<2048, 256, 0, stream>>>(y1, w2t, y2, st2);
    norm2_kernel<<<16384, 256, 0, stream>>>(y2, st2, out);
}